// Round 1
// 1346.527 us; speedup vs baseline: 1.8305x; 1.8305x over previous
//
#include <hip/hip_runtime.h>
#include <math.h>

#define NN 100000
#define NE 3200000
#define CAP 80   /* CSR slots per node; Poisson(32) => P(any node >80) ~ 1e-7; overflow falls back to atomics */

#define SQ3f   1.7320508075688772f
#define SQ5f   2.2360679774997896f
#define SQ15f  3.8729833462074170f
#define INV_SQ3f 0.57735026918962576f
#define INV_SQ5f 0.44721359549995794f
#define C_Hf   0.31622776601683794f   /* sqrt(15)/2 / sqrt(37.5) */
#define C_S5f  0.36514837167011072f   /* sqrt(5)   / sqrt(37.5) */
#define C_S5Hf 0.18257418583505536f   /* sqrt(5)/2 / sqrt(37.5) */
#define ERBF_K 0.44721359549995794f   /* sqrt(2/10) */
#define PI_OVER_CUT 0.31415926535897931f
#define INV_CUT 0.1f
#define EPSf 1e-5f

#define ERBF_OFF 48000000L   /* NN*480 */
#define ERSH_OFF 99200000L   /* +NE*16 */

__device__ __forceinline__ float bf2f(unsigned short b){
  union { unsigned int u; float f; } c; c.u = ((unsigned int)b) << 16; return c.f;
}
__device__ __forceinline__ unsigned short f2bf(float f){
  union { float f; unsigned int u; } c; c.f = f;
  unsigned int u = c.u;
  return (unsigned short)((u + 0x7fffu + ((u >> 16) & 1u)) >> 16);
}
template<bool BF> __device__ __forceinline__ float ldf(const void* p, long i){
  if (BF) return bf2f(((const unsigned short*)p)[i]);
  return ((const float*)p)[i];
}
template<bool BF> __device__ __forceinline__ void stf(void* p, long i, float v){
  if (BF) ((unsigned short*)p)[i] = f2bf(v);
  else ((float*)p)[i] = v;
}
__device__ __forceinline__ float sigf(float v){ return 1.0f / (1.0f + expf(-v)); }

// vectorized gathers (memcpy -> widest load the alignment permits)
template<bool BF> __device__ __forceinline__ void ld_pos3(const void* pos, long idx, float r[3]){
  if (BF){
    const unsigned short* p = (const unsigned short*)pos + idx*3;
    unsigned int w; __builtin_memcpy(&w, p, 4);
    r[0] = bf2f((unsigned short)(w & 0xffffu));
    r[1] = bf2f((unsigned short)(w >> 16));
    r[2] = bf2f(p[2]);
  } else {
    const float* p = (const float*)pos + idx*3;
    float2 v; __builtin_memcpy(&v, p, 8);
    r[0] = v.x; r[1] = v.y; r[2] = p[2];
  }
}
template<bool BF> __device__ __forceinline__ void ld_x9(const void* x, long row, float o[9]){
  if (BF){
    const unsigned short* p = (const unsigned short*)x + row*9;
    uint4 w; __builtin_memcpy(&w, p, 16);
    o[0]=bf2f((unsigned short)(w.x & 0xffffu)); o[1]=bf2f((unsigned short)(w.x >> 16));
    o[2]=bf2f((unsigned short)(w.y & 0xffffu)); o[3]=bf2f((unsigned short)(w.y >> 16));
    o[4]=bf2f((unsigned short)(w.z & 0xffffu)); o[5]=bf2f((unsigned short)(w.z >> 16));
    o[6]=bf2f((unsigned short)(w.w & 0xffffu)); o[7]=bf2f((unsigned short)(w.w >> 16));
    o[8]=bf2f(p[8]);
  } else {
    const float* p = (const float*)x + row*9;
    float4 A, B; __builtin_memcpy(&A, p, 16); __builtin_memcpy(&B, p + 4, 16);
    o[0]=A.x; o[1]=A.y; o[2]=A.z; o[3]=A.w;
    o[4]=B.x; o[5]=B.y; o[6]=B.z; o[7]=B.w;
    o[8]=p[8];
  }
}

__device__ __forceinline__ void edge_geom(float vx, float vy, float vz,
    float& ux, float& uy, float& uz, float sh[5],
    float& g0, float& g1, float& g2, float& dist, float& rinv, float& fc)
{
  dist = sqrtf(vx*vx + vy*vy + vz*vz);
  rinv = 1.0f / fmaxf(dist, 1e-12f);
  ux = vx*rinv; uy = vy*rinv; uz = vz*rinv;
  sh[0] = SQ15f*ux*uz;
  sh[1] = SQ15f*ux*uy;
  sh[2] = SQ5f*(uy*uy - 0.5f*(ux*ux + uz*uz));
  sh[3] = SQ15f*uy*uz;
  sh[4] = 0.5f*SQ15f*(uz*uz - ux*ux);
  float d = dist * INV_CUT;
  float d2 = d*d, d5 = d2*d2*d;
  fc = 1.0f - 21.0f*d5 + 35.0f*d5*d - 15.0f*d5*d2;
  fc = (d < 1.0f) ? fc : 0.0f;
  float eg = expf(-d2);
  g0 = eg*fc; g1 = g0*d; g2 = g1*d;
}

// ---------------------------------------------------------------------------
// init: detect dtype (bf16 vs f32) from x, and compute W222 (5x5x5) in f64.
// ---------------------------------------------------------------------------
__global__ void init_kernel(const void* __restrict__ x, int* __restrict__ flag,
                            float* __restrict__ w222){
  if (threadIdx.x != 0 || blockIdx.x != 0) return;
  int isbf = 1;
  const unsigned short* p = (const unsigned short*)x;
  for (int i = 0; i < 256; i++){
    float v = bf2f(p[i]);
    if (!(fabsf(v) < 1e4f)) { isbf = 0; break; }
  }
  *flag = isbf;

  double A[5][3][3];
  for (int m = 0; m < 5; m++) for (int i = 0; i < 3; i++) for (int j = 0; j < 3; j++) A[m][i][j] = 0.0;
  const double h = 1.9364916731037085;  // sqrt(15)/2
  const double s5 = 2.2360679774997896; // sqrt(5)
  A[0][0][2] = h;  A[0][2][0] = h;
  A[1][0][1] = h;  A[1][1][0] = h;
  A[2][0][0] = -0.5*s5; A[2][1][1] = s5; A[2][2][2] = -0.5*s5;
  A[3][1][2] = h;  A[3][2][1] = h;
  A[4][0][0] = -h; A[4][2][2] = h;
  double W[125];
  for (int m = 0; m < 5; m++) for (int n = 0; n < 5; n++) for (int q = 0; q < 5; q++){
    double s = 0.0;
    for (int i = 0; i < 3; i++) for (int k = 0; k < 3; k++) for (int j = 0; j < 3; j++)
      s += A[m][i][k] * A[n][k][j] * A[q][j][i];
    W[m*25 + n*5 + q] = s;
  }
  double nrm2 = 0.0;
  double W2[125];
  for (int m = 0; m < 5; m++) for (int n = 0; n < 5; n++) for (int q = 0; q < 5; q++){
    double s = W[m*25 + n*5 + q] + W[n*25 + m*5 + q];
    W2[m*25 + n*5 + q] = s;
    nrm2 += s * s;
  }
  double inv = 1.0 / sqrt(nrm2);
  for (int i = 0; i < 125; i++) w222[i] = (float)(W2[i] * inv);
}

// ---------------------------------------------------------------------------
// Edge kernel: build CSR (1 int atomic/edge instead of 9 f32 atomics),
// write erbf (E x 16) and ersh (E x 9). Overflow -> direct atomics into a.
// ---------------------------------------------------------------------------
template<bool BF>
__global__ __launch_bounds__(256) void edge_kernel(
    const void* __restrict__ x, const void* __restrict__ pos, const int* __restrict__ ei,
    const int* __restrict__ flag, int* __restrict__ cnt, int* __restrict__ csr,
    float* __restrict__ a, void* __restrict__ out)
{
  if ((*flag != 0) != BF) return;
  const int e = blockIdx.x * 256 + threadIdx.x;
  const int src = ei[e], dst = ei[NE + e];
  float sp[3], dp[3];
  ld_pos3<BF>(pos, src, sp);
  ld_pos3<BF>(pos, dst, dp);
  // permutation: new (x,y,z) = (pos1, pos2, pos0)
  float vx = dp[1]-sp[1], vy = dp[2]-sp[2], vz = dp[0]-sp[0];
  float ux, uy, uz, sh[5], g0, g1, g2, dist, rinv, fc;
  edge_geom(vx, vy, vz, ux, uy, uz, sh, g0, g1, g2, dist, rinv, fc);

  // CSR slot claim (single int atomic per edge)
  int slot = atomicAdd(&cnt[dst], 1);
  if (slot < CAP){
    csr[(long)dst*CAP + slot] = src;
  } else {
    // rare overflow path: accumulate directly (keeps correctness independent of CAP)
    float xr[9]; ld_x9<BF>(x, src, xr);
    float* ad = a + (long)dst * 9;
    atomicAdd(ad + 0, xr[0] * g0);
    atomicAdd(ad + 1, xr[1] * (SQ3f*ux) * g1);
    atomicAdd(ad + 2, xr[2] * (SQ3f*uy) * g1);
    atomicAdd(ad + 3, xr[3] * (SQ3f*uz) * g1);
    atomicAdd(ad + 4, xr[4] * sh[0] * g2);
    atomicAdd(ad + 5, xr[5] * sh[1] * g2);
    atomicAdd(ad + 6, xr[6] * sh[2] * g2);
    atomicAdd(ad + 7, xr[7] * sh[3] * g2);
    atomicAdd(ad + 8, xr[8] * sh[4] * g2);
  }

  // erbf via Chebyshev recurrence: sin((n+1)t) = 2 cos(t) sin(nt) - sin((n-1)t)
  float t = PI_OVER_CUT * dist;
  float st = sinf(t), c2t = 2.0f*cosf(t);
  float kk = ERBF_K * fc * rinv;
  float snm1 = 0.0f, sn = st;
  if (BF){
    unsigned short eb[16];
    #pragma unroll
    for (int n = 0; n < 16; n++){
      eb[n] = f2bf(sn * kk);
      float nx = c2t*sn - snm1; snm1 = sn; sn = nx;
    }
    uint4* q = (uint4*)((unsigned short*)out + ERBF_OFF + (long)e*16);
    q[0] = make_uint4((unsigned)eb[0] | ((unsigned)eb[1] << 16),
                      (unsigned)eb[2] | ((unsigned)eb[3] << 16),
                      (unsigned)eb[4] | ((unsigned)eb[5] << 16),
                      (unsigned)eb[6] | ((unsigned)eb[7] << 16));
    q[1] = make_uint4((unsigned)eb[8]  | ((unsigned)eb[9]  << 16),
                      (unsigned)eb[10] | ((unsigned)eb[11] << 16),
                      (unsigned)eb[12] | ((unsigned)eb[13] << 16),
                      (unsigned)eb[14] | ((unsigned)eb[15] << 16));
  } else {
    float er[16];
    #pragma unroll
    for (int n = 0; n < 16; n++){
      er[n] = sn * kk;
      float nx = c2t*sn - snm1; snm1 = sn; sn = nx;
    }
    float4* q = (float4*)((float*)out + ERBF_OFF + (long)e*16);
    q[0] = make_float4(er[0], er[1], er[2], er[3]);
    q[1] = make_float4(er[4], er[5], er[6], er[7]);
    q[2] = make_float4(er[8], er[9], er[10], er[11]);
    q[3] = make_float4(er[12], er[13], er[14], er[15]);
  }
  // ersh = sph_l012(-vec): l=0 unchanged, l=1 negated, l=2 even
  long sb = ERSH_OFF + (long)e*9;
  stf<BF>(out, sb + 0, 1.0f);
  stf<BF>(out, sb + 1, -SQ3f*ux);
  stf<BF>(out, sb + 2, -SQ3f*uy);
  stf<BF>(out, sb + 3, -SQ3f*uz);
  stf<BF>(out, sb + 4, sh[0]);
  stf<BF>(out, sb + 5, sh[1]);
  stf<BF>(out, sb + 6, sh[2]);
  stf<BF>(out, sb + 7, sh[3]);
  stf<BF>(out, sb + 8, sh[4]);
}

// ---------------------------------------------------------------------------
// Aggregation: one wave per node. Gather src rows from CSR, recompute the
// message (VALU is idle anyway), wave-reduce, plain store. Zero atomics.
// ---------------------------------------------------------------------------
template<bool BF>
__global__ __launch_bounds__(256) void agg_kernel(
    const void* __restrict__ x, const void* __restrict__ pos,
    const int* __restrict__ flag, const int* __restrict__ cnt,
    const int* __restrict__ csr, float* __restrict__ a)
{
  if ((*flag != 0) != BF) return;
  const int tid = threadIdx.x;
  const int n = blockIdx.x * 4 + (tid >> 6);
  const int lane = tid & 63;
  float dp[3]; ld_pos3<BF>(pos, n, dp);
  int cn = cnt[n];
  int cc = cn < CAP ? cn : CAP;
  float acc[9];
  #pragma unroll
  for (int j = 0; j < 9; j++) acc[j] = 0.f;
  for (int slot = lane; slot < cc; slot += 64){
    int src = csr[(long)n*CAP + slot];
    float sp[3]; ld_pos3<BF>(pos, src, sp);
    float xr[9]; ld_x9<BF>(x, src, xr);
    float vx = dp[1]-sp[1], vy = dp[2]-sp[2], vz = dp[0]-sp[0];
    float ux, uy, uz, sh[5], g0, g1, g2, dist, rinv, fc;
    edge_geom(vx, vy, vz, ux, uy, uz, sh, g0, g1, g2, dist, rinv, fc);
    acc[0] += xr[0] * g0;
    acc[1] += xr[1] * (SQ3f*ux) * g1;
    acc[2] += xr[2] * (SQ3f*uy) * g1;
    acc[3] += xr[3] * (SQ3f*uz) * g1;
    acc[4] += xr[4] * sh[0] * g2;
    acc[5] += xr[5] * sh[1] * g2;
    acc[6] += xr[6] * sh[2] * g2;
    acc[7] += xr[7] * sh[3] * g2;
    acc[8] += xr[8] * sh[4] * g2;
  }
  #pragma unroll
  for (int j = 0; j < 9; j++){
    #pragma unroll
    for (int off = 32; off > 0; off >>= 1)
      acc[j] += __shfl_xor(acc[j], off, 64);
  }
  if (lane == 0){
    float* an = a + (long)n * 9;
    #pragma unroll
    for (int j = 0; j < 9; j++) an[j] += acc[j];  // += picks up rare overflow-atomic contributions
  }
}

// ---------------------------------------------------------------------------
// C0: h0 = sigmoid(out0 @ W0a) @ W0b -> out cols [0,128); stats sum/sumsq
// ---------------------------------------------------------------------------
template<bool BF>
__global__ __launch_bounds__(256) void c0_kernel(const float* __restrict__ a,
    const void* __restrict__ tp, const void* __restrict__ w0a, const void* __restrict__ w0b,
    const int* __restrict__ flag, void* __restrict__ out, float* __restrict__ stats)
{
  if ((*flag != 0) != BF) return;
  __shared__ float W0aL[384];
  __shared__ float W0bL[16384];
  __shared__ float h0L[16*128];
  __shared__ float o0L[16*3];
  __shared__ float sumL[128], sqL[128];
  const int tid = threadIdx.x;
  const int c = tid & 127, half = tid >> 7;
  const int n0 = blockIdx.x * 16;
  for (int i = tid; i < 384; i += 256) W0aL[i] = ldf<BF>(w0a, i);
  for (int i = tid; i < 16384; i += 256) W0bL[i] = ldf<BF>(w0b, i);
  if (tid < 128){ sumL[tid] = 0.f; sqL[tid] = 0.f; }
  if (tid < 48){
    int n = tid / 3, j = tid - n*3;
    const float* an = a + (long)(n0 + n) * 9;
    float tpj = ldf<BF>(tp, j);
    float v;
    if (j == 0)      v = tpj * an[0]*an[0];
    else if (j == 1) v = tpj * (an[1]*an[1] + an[2]*an[2] + an[3]*an[3]) * INV_SQ3f;
    else             v = tpj * (an[4]*an[4] + an[5]*an[5] + an[6]*an[6] + an[7]*an[7] + an[8]*an[8]) * INV_SQ5f;
    o0L[tid] = v;
  }
  __syncthreads();
  #pragma unroll
  for (int i = 0; i < 8; i++){
    int n = half*8 + i;
    float pre = o0L[n*3]*W0aL[c] + o0L[n*3+1]*W0aL[128+c] + o0L[n*3+2]*W0aL[256+c];
    h0L[n*128 + c] = sigf(pre);
  }
  __syncthreads();
  float acc[8];
  #pragma unroll
  for (int i = 0; i < 8; i++) acc[i] = 0.f;
  for (int k = 0; k < 128; k++){
    float w = W0bL[k*128 + c];
    #pragma unroll
    for (int i = 0; i < 8; i++) acc[i] += h0L[(half*8 + i)*128 + k] * w;
  }
  float lsum = 0.f, lsq = 0.f;
  #pragma unroll
  for (int i = 0; i < 8; i++){
    int n = half*8 + i;
    stf<BF>(out, (long)(n0 + n)*480 + c, acc[i]);
    lsum += acc[i]; lsq += acc[i]*acc[i];
  }
  atomicAdd(&sumL[c], lsum); atomicAdd(&sqL[c], lsq);
  __syncthreads();
  if (tid < 128){ atomicAdd(&stats[tid], sumL[tid]); atomicAdd(&stats[128 + tid], sqL[tid]); }
}

// ---------------------------------------------------------------------------
// C1: h1 path (v<64, m<3) -> out cols [128,320); stats1 = sum_n sum_m h1b^2
// ---------------------------------------------------------------------------
template<bool BF>
__global__ __launch_bounds__(256) void c1_kernel(const float* __restrict__ a,
    const void* __restrict__ tp, const void* __restrict__ w1a, const void* __restrict__ w1b,
    const int* __restrict__ flag, void* __restrict__ out, float* __restrict__ stats1)
{
  if ((*flag != 0) != BF) return;
  __shared__ float W1aL[256];
  __shared__ float W1bL[4096];
  __shared__ float h1L[32*64*3];
  __shared__ float o1L[32*12];
  __shared__ float ssL[64];
  const int tid = threadIdx.x;
  const int v = tid & 63, ng = tid >> 6;
  const int n0 = blockIdx.x * 32;
  for (int i = tid; i < 256; i += 256) W1aL[i] = ldf<BF>(w1a, i);
  for (int i = tid; i < 4096; i += 256) W1bL[i] = ldf<BF>(w1b, i);
  if (tid < 64) ssL[tid] = 0.f;
  float tp3 = ldf<BF>(tp, 3), tp4 = ldf<BF>(tp, 4), tp5 = ldf<BF>(tp, 5), tp6 = ldf<BF>(tp, 6);
  for (int idx = tid; idx < 384; idx += 256){
    int n = idx / 12, r = idx - n*12;
    int u = r / 3, m = r - u*3;
    const float* an = a + (long)(n0 + n) * 9;
    float s1x = an[1], s1y = an[2], s1z = an[3];
    float val;
    if (u == 0)      val = tp3 * an[0] * an[1 + m];
    else if (u == 1) val = tp4 * an[1 + m] * an[0];
    else {
      float e1m;
      if (m == 0)      e1m = C_Hf*(an[4]*s1z + an[5]*s1y - an[8]*s1x) - C_S5Hf*an[6]*s1x;
      else if (m == 1) e1m = C_Hf*(an[5]*s1x + an[7]*s1z) + C_S5f*an[6]*s1y;
      else             e1m = C_Hf*(an[4]*s1x + an[7]*s1y + an[8]*s1z) - C_S5Hf*an[6]*s1z;
      val = (u == 2 ? tp5 : tp6) * e1m;
    }
    o1L[idx] = val;
  }
  __syncthreads();
  #pragma unroll
  for (int i = 0; i < 8; i++){
    int n = ng*8 + i;
    float h[3];
    #pragma unroll
    for (int m = 0; m < 3; m++){
      float s = 0.f;
      #pragma unroll
      for (int u = 0; u < 4; u++) s += o1L[n*12 + u*3 + m] * W1aL[u*64 + v];
      h[m] = s;
    }
    float g = sigf(sqrtf(h[0]*h[0] + h[1]*h[1] + h[2]*h[2]));
    int b = (n*64 + v)*3;
    h1L[b] = h[0]*g; h1L[b+1] = h[1]*g; h1L[b+2] = h[2]*g;
  }
  __syncthreads();
  float ss = 0.f;
  for (int i = 0; i < 8; i++){
    int n = ng*8 + i;
    float a0 = 0.f, a1 = 0.f, a2 = 0.f;
    for (int u = 0; u < 64; u++){
      float w = W1bL[u*64 + v];
      const float* hp = &h1L[(n*64 + u)*3];
      a0 += hp[0]*w; a1 += hp[1]*w; a2 += hp[2]*w;
    }
    long b = (long)(n0 + n)*480 + 128 + v*3;
    stf<BF>(out, b, a0); stf<BF>(out, b+1, a1); stf<BF>(out, b+2, a2);
    ss += a0*a0 + a1*a1 + a2*a2;
  }
  atomicAdd(&ssL[v], ss);
  __syncthreads();
  if (tid < 64) atomicAdd(&stats1[tid], ssL[tid]);
}

// ---------------------------------------------------------------------------
// C2: h2 path (v<32, m<5) -> out cols [320,480); stats2 = sum_n sum_m h2b^2
// ---------------------------------------------------------------------------
template<bool BF>
__global__ __launch_bounds__(256) void c2_kernel(const float* __restrict__ a,
    const void* __restrict__ tp, const void* __restrict__ w2a, const void* __restrict__ w2b,
    const int* __restrict__ flag, void* __restrict__ out, float* __restrict__ stats2,
    const float* __restrict__ w222)
{
  if ((*flag != 0) != BF) return;
  __shared__ float W2aL[128];
  __shared__ float W2bL[1024];
  __shared__ float h2L[32*32*5];
  __shared__ float o2L[32*20];
  __shared__ float ssL[32];
  const int tid = threadIdx.x;
  const int v = tid & 31, ng = tid >> 5;
  const int n0 = blockIdx.x * 32;
  for (int i = tid; i < 128; i += 256) W2aL[i] = ldf<BF>(w2a, i);
  for (int i = tid; i < 1024; i += 256) W2bL[i] = ldf<BF>(w2b, i);
  if (tid < 32) ssL[tid] = 0.f;
  float tp7 = ldf<BF>(tp, 7), tp8 = ldf<BF>(tp, 8), tp9 = ldf<BF>(tp, 9), tp10 = ldf<BF>(tp, 10);
  for (int idx = tid; idx < 640; idx += 256){
    int n = idx / 20, r = idx - n*20, u = r / 5, m = r - u*5;
    const float* an = a + (long)(n0 + n) * 9;
    float x1 = an[1], y1 = an[2], z1 = an[3];
    float val;
    if (u == 0)      val = tp7 * an[0] * an[4 + m];
    else if (u == 1) val = tp8 * an[4 + m] * an[0];
    else if (u == 2){
      float pm;
      if (m == 0)      pm = 2.f*C_Hf*x1*z1;
      else if (m == 1) pm = 2.f*C_Hf*x1*y1;
      else if (m == 2) pm = C_S5f*y1*y1 - C_S5Hf*(x1*x1 + z1*z1);
      else if (m == 3) pm = 2.f*C_Hf*y1*z1;
      else             pm = C_Hf*(z1*z1 - x1*x1);
      val = tp9 * pm;
    } else {
      float q = 0.f;
      #pragma unroll
      for (int aa = 0; aa < 5; aa++){
        float sa = an[4 + aa];
        #pragma unroll
        for (int bb = 0; bb < 5; bb++) q += w222[aa*25 + bb*5 + m] * sa * an[4 + bb];
      }
      val = tp10 * q;
    }
    o2L[idx] = val;
  }
  __syncthreads();
  #pragma unroll
  for (int i = 0; i < 4; i++){
    int n = ng*4 + i;
    float h[5];
    #pragma unroll
    for (int m = 0; m < 5; m++){
      float s = 0.f;
      #pragma unroll
      for (int u = 0; u < 4; u++) s += o2L[n*20 + u*5 + m] * W2aL[u*32 + v];
      h[m] = s;
    }
    float g = sigf(sqrtf(h[0]*h[0] + h[1]*h[1] + h[2]*h[2] + h[3]*h[3] + h[4]*h[4]));
    int b = (n*32 + v)*5;
    #pragma unroll
    for (int m = 0; m < 5; m++) h2L[b + m] = h[m]*g;
  }
  __syncthreads();
  float ss = 0.f;
  #pragma unroll
  for (int i = 0; i < 4; i++){
    int n = ng*4 + i;
    float acc[5] = {0.f, 0.f, 0.f, 0.f, 0.f};
    for (int u = 0; u < 32; u++){
      float w = W2bL[u*32 + v];
      const float* hp = &h2L[(n*32 + u)*5];
      #pragma unroll
      for (int m = 0; m < 5; m++) acc[m] += hp[m]*w;
    }
    long b = (long)(n0 + n)*480 + 320 + v*5;
    #pragma unroll
    for (int m = 0; m < 5; m++) stf<BF>(out, b + m, acc[m]);
    #pragma unroll
    for (int m = 0; m < 5; m++) ss += acc[m]*acc[m];
  }
  atomicAdd(&ssL[v], ss);
  __syncthreads();
  if (tid < 32) atomicAdd(&stats2[tid], ssL[tid]);
}

// ---------------------------------------------------------------------------
__global__ void finalize_kernel(const float* __restrict__ stats, float* __restrict__ params){
  int t = threadIdx.x;
  if (t < 128){
    float mean = stats[t] * (1.0f/NN);
    float var  = stats[128 + t] * (1.0f/NN) - mean*mean;
    params[t] = mean;
    params[128 + t] = 1.0f / sqrtf(fmaxf(var, 0.f) + EPSf);
  }
  if (t < 64) params[256 + t] = 1.0f / sqrtf(stats[256 + t] * (1.0f/(NN*3.0f)) + EPSf);
  if (t < 32) params[320 + t] = 1.0f / sqrtf(stats[320 + t] * (1.0f/(NN*5.0f)) + EPSf);
}

template<bool BF>
__global__ __launch_bounds__(256) void norm_kernel(const int* __restrict__ flag,
    void* __restrict__ out, const float* __restrict__ params)
{
  if ((*flag != 0) != BF) return;
  const long n = blockIdx.x;
  const int t = threadIdx.x;
  #pragma unroll
  for (int j0 = 0; j0 < 2; j0++){
    int j = t + j0*256;
    if (j < 480){
      long idx = n*480 + j;
      float vv = ldf<BF>(out, idx);
      float r;
      if (j < 128)      r = (vv - params[j]) * params[128 + j];
      else if (j < 320) r = vv * params[256 + (j - 128)/3];
      else              r = vv * params[320 + (j - 320)/5];
      stf<BF>(out, idx, r);
    }
  }
}

// ---------------------------------------------------------------------------
extern "C" void kernel_launch(void* const* d_in, const int* in_sizes, int n_in,
                              void* d_out, int out_size, void* d_ws, size_t ws_size,
                              hipStream_t stream) {
  const void* x   = d_in[0];
  const void* pos = d_in[1];
  const int*  ei  = (const int*)d_in[2];
  const void* tp  = d_in[3];
  const void* w0a = d_in[4];
  const void* w1a = d_in[5];
  const void* w2a = d_in[6];
  const void* w0b = d_in[7];
  const void* w1b = d_in[8];
  const void* w2b = d_in[9];

  // ws layout: [0,4) flag | [64, 400064) cnt (NN int) | [400064, 4000064) a (NN*9 f32)
  //          | [4000064, +352*4) stats | params (352 f32) | w222 (125 f32)
  int*   flag   = (int*)d_ws;
  int*   cnt    = (int*)((char*)d_ws + 64);
  float* a      = (float*)((char*)d_ws + 400064);
  float* stats  = (float*)((char*)d_ws + 4000064);
  float* params = stats + 352;
  float* w222   = params + 352;

  // CSR scratch lives in d_out's node region ([0, 32MB) < 96MB bf16 node region),
  // fully overwritten later by c0/c1/c2+norm.
  int* csr = (int*)d_out;

  hipMemsetAsync(d_ws, 0, 4001472, stream);
  init_kernel<<<1, 64, 0, stream>>>(x, flag, w222);

  edge_kernel<true ><<<NE/256, 256, 0, stream>>>(x, pos, ei, flag, cnt, csr, a, d_out);
  edge_kernel<false><<<NE/256, 256, 0, stream>>>(x, pos, ei, flag, cnt, csr, a, d_out);

  agg_kernel<true ><<<NN/4, 256, 0, stream>>>(x, pos, flag, cnt, csr, a);
  agg_kernel<false><<<NN/4, 256, 0, stream>>>(x, pos, flag, cnt, csr, a);

  c0_kernel<true ><<<NN/16, 256, 0, stream>>>(a, tp, w0a, w0b, flag, d_out, stats);
  c0_kernel<false><<<NN/16, 256, 0, stream>>>(a, tp, w0a, w0b, flag, d_out, stats);
  c1_kernel<true ><<<NN/32, 256, 0, stream>>>(a, tp, w1a, w1b, flag, d_out, stats + 256);
  c1_kernel<false><<<NN/32, 256, 0, stream>>>(a, tp, w1a, w1b, flag, d_out, stats + 256);
  c2_kernel<true ><<<NN/32, 256, 0, stream>>>(a, tp, w2a, w2b, flag, d_out, stats + 320, w222);
  c2_kernel<false><<<NN/32, 256, 0, stream>>>(a, tp, w2a, w2b, flag, d_out, stats + 320, w222);

  finalize_kernel<<<1, 128, 0, stream>>>(stats, params);

  norm_kernel<true ><<<NN, 256, 0, stream>>>(flag, d_out, params);
  norm_kernel<false><<<NN, 256, 0, stream>>>(flag, d_out, params);
}